// Round 5
// baseline (2283.061 us; speedup 1.0000x reference)
//
#include <hip/hip_runtime.h>
#include <cmath>

// Problem constants
#define B_   512
#define L_   200
#define V_   50000
#define E_   256
#define H_   128     // per-direction hidden
#define G4H_ 512     // 4*H
#define D_   256     // 2*H
#define T_   6

__device__ __forceinline__ float sigmoidf_(float x) { return 1.0f / (1.0f + __expf(-x)); }
__device__ __forceinline__ float leakyf_(float x)   { return x >= 0.0f ? x : 0.01f * x; }

// DPP quad-perm add (VALU pipe — NOT ds_bpermute/LDS). CTRL: xor1=0xB1, xor2=0x4E.
template<int CTRL>
__device__ __forceinline__ float dpp_add_(float x) {
    const int m = __builtin_amdgcn_mov_dpp(__float_as_int(x), CTRL, 0xF, 0xF, true);
    return x + __int_as_float(m);
}

// ---------------------------------------------------------------------------
// Shared 256-wide GEMM tile geometry.
// Theory: 128x128/8x8 tiles are LDS-instr-bound (3 b128 per 32 FMA, per-CU
// LDS:VALU = 288:128 -> measured VALUBusy 48.8% on fused_mlp matches).
// 128x256/8x16: 6 b128 per 128 FMA -> per-CU 576:512 -> ~85% VALU.
// VGPR: 128 acc + 8 a + 16 bb + 12 prefetch + addr ~= 180 < 256 (no spill).
// ---------------------------------------------------------------------------
#define XBM  128
#define XBK  8
#define XASTR 132
#define XBSTR 264

// ---------------------------------------------------------------------------
// K1: xg GEMM, 128x256 tile, 8x16 micro-tile, BK=8, ping-pong double buffer.
// ---------------------------------------------------------------------------
__global__ __launch_bounds__(256) void gemm_xg_chunk(
    const int* __restrict__ sent, const float* __restrict__ emb,
    const float* __restrict__ Wf, const float* __restrict__ Wb,
    const float* __restrict__ bihf, const float* __restrict__ bhhf,
    const float* __restrict__ bihb, const float* __restrict__ bhhb,
    float* __restrict__ xgc, int c0, int tc)
{
    __shared__ float As[2][XBK][XASTR];
    __shared__ float Bs[2][XBK][XBSTR];
    __shared__ int   tok[XBM];

    const int bm  = blockIdx.x;       // 0 .. 8*tc-1
    const int bn  = blockIdx.y;       // 0..1 (N=512 per dir)
    const int tid = threadIdx.x;
    const int half = B_ * tc;         // rows per direction
    const int dir  = (bm * XBM) >= half;  // uniform (B*tc % 128 == 0)

    if (tid < XBM) {
        const int vm  = bm * XBM + tid;
        const int rem = vm - dir * half;
        const int b   = rem / tc;
        const int ti  = rem - b * tc;
        const int s   = c0 + ti;
        const int t   = dir ? (L_ - 1 - s) : s;
        tok[tid] = sent[b * L_ + t];
    }
    __syncthreads();

    const int tx = tid & 15;
    const int ty = tid >> 4;
    const int n0 = bn * 256;

    const float* W   = dir ? Wb   : Wf;
    const float* bih = dir ? bihb : bihf;
    const float* bhh = dir ? bhhb : bhhf;

    const int am = tid >> 1;          // staging row 0..127
    const int ak = (tid & 1) * 4;     // staging k 0 or 4

    const float* arow  = emb + (size_t)tok[am] * E_ + ak;
    const float* brow0 = W + (size_t)(n0 + am) * E_ + ak;
    const float* brow1 = W + (size_t)(n0 + 128 + am) * E_ + ak;

    float acc[8][16];
#pragma unroll
    for (int i = 0; i < 8; ++i)
#pragma unroll
        for (int j = 0; j < 16; ++j) acc[i][j] = 0.0f;

    // prologue: stage slice 0
    {
        const float4 a  = *(const float4*)(arow);
        const float4 b0 = *(const float4*)(brow0);
        const float4 b1 = *(const float4*)(brow1);
        As[0][ak + 0][am] = a.x;  As[0][ak + 1][am] = a.y;
        As[0][ak + 2][am] = a.z;  As[0][ak + 3][am] = a.w;
        Bs[0][ak + 0][am] = b0.x; Bs[0][ak + 1][am] = b0.y;
        Bs[0][ak + 2][am] = b0.z; Bs[0][ak + 3][am] = b0.w;
        Bs[0][ak + 0][128 + am] = b1.x; Bs[0][ak + 1][128 + am] = b1.y;
        Bs[0][ak + 2][128 + am] = b1.z; Bs[0][ak + 3][128 + am] = b1.w;
    }
    __syncthreads();

    const int NIT = E_ / XBK;         // 32
    for (int it = 0; it < NIT; ++it) {
        const int cur = it & 1;
        const int kn  = (it + 1) * XBK;
        float4 na, nb0, nb1;
        if (kn < E_) {
            na  = *(const float4*)(arow + kn);
            nb0 = *(const float4*)(brow0 + kn);
            nb1 = *(const float4*)(brow1 + kn);
        }
#pragma unroll
        for (int k = 0; k < XBK; ++k) {
            float a[8], bb[16];
            *(float4*)a         = *(const float4*)&As[cur][k][ty * 4];
            *(float4*)(a + 4)   = *(const float4*)&As[cur][k][64 + ty * 4];
            *(float4*)(bb)      = *(const float4*)&Bs[cur][k][tx * 4];
            *(float4*)(bb + 4)  = *(const float4*)&Bs[cur][k][64 + tx * 4];
            *(float4*)(bb + 8)  = *(const float4*)&Bs[cur][k][128 + tx * 4];
            *(float4*)(bb + 12) = *(const float4*)&Bs[cur][k][192 + tx * 4];
#pragma unroll
            for (int i = 0; i < 8; ++i)
#pragma unroll
                for (int j = 0; j < 16; ++j) acc[i][j] += a[i] * bb[j];
        }
        if (kn < E_) {
            const int nxt = cur ^ 1;
            As[nxt][ak + 0][am] = na.x;  As[nxt][ak + 1][am] = na.y;
            As[nxt][ak + 2][am] = na.z;  As[nxt][ak + 3][am] = na.w;
            Bs[nxt][ak + 0][am] = nb0.x; Bs[nxt][ak + 1][am] = nb0.y;
            Bs[nxt][ak + 2][am] = nb0.z; Bs[nxt][ak + 3][am] = nb0.w;
            Bs[nxt][ak + 0][128 + am] = nb1.x; Bs[nxt][ak + 1][128 + am] = nb1.y;
            Bs[nxt][ak + 2][128 + am] = nb1.z; Bs[nxt][ak + 3][128 + am] = nb1.w;
        }
        __syncthreads();
    }

    // epilogue: bias + store (4 col-quadrants of 64)
    float bias[16];
#pragma unroll
    for (int qd = 0; qd < 4; ++qd) {
        const int cb = n0 + qd * 64 + tx * 4;
#pragma unroll
        for (int j = 0; j < 4; ++j) bias[qd * 4 + j] = bih[cb + j] + bhh[cb + j];
    }
#pragma unroll
    for (int i = 0; i < 8; ++i) {
        const int row = bm * XBM + ((i < 4) ? (ty * 4 + i) : (64 + ty * 4 + i - 4));
        float* dst = xgc + (size_t)row * G4H_;
#pragma unroll
        for (int qd = 0; qd < 4; ++qd) {
            float4 v;
            v.x = acc[i][qd * 4 + 0] + bias[qd * 4 + 0];
            v.y = acc[i][qd * 4 + 1] + bias[qd * 4 + 1];
            v.z = acc[i][qd * 4 + 2] + bias[qd * 4 + 2];
            v.w = acc[i][qd * 4 + 3] + bias[qd * 4 + 3];
            *(float4*)(dst + n0 + qd * 64 + tx * 4) = v;
        }
    }
}

// ---------------------------------------------------------------------------
// K2 (v3, unchanged): LSTM scan, 4-way split-K + DPP quad reduce.
// ---------------------------------------------------------------------------
__global__ __launch_bounds__(512, 2) void lstm_scan_chunk(
    const float* __restrict__ xgc,
    const float* __restrict__ Whh_f, const float* __restrict__ Whh_b,
    float* __restrict__ state, float* __restrict__ hcat, int c0, int tc)
{
    const int wg  = blockIdx.x;      // 0..255
    const int dir = wg >> 7;
    const int b0  = (wg & 127) * 4;  // 4 samples per wg
    const int tid = threadIdx.x;     // 0..511

    const int q  = tid & 3;          // k-quarter
    const int g2 = tid >> 2;         // gate-group 0..127
    const int j_ = g2;               // nonlin: hidden j
    const int s_ = q;                // nonlin: sample

    const float* Whh = dir ? Whh_b : Whh_f;

    // quarter-rows of 4 gates: 4 x 32 = 128 VGPRs, statically indexed
    float w[4][32];
#pragma unroll
    for (int p = 0; p < 4; ++p) {
        const float* wr = Whh + (size_t)(g2 + 128 * p) * H_ + q * 32;
#pragma unroll
        for (int kk = 0; kk < 32; kk += 4) {
            const float4 v = *(const float4*)(wr + kk);
            w[p][kk] = v.x; w[p][kk + 1] = v.y; w[p][kk + 2] = v.z; w[p][kk + 3] = v.w;
        }
    }

    __shared__ float hbuf[4 * 132];   // h: block q' stride 132, elem kk*4+s
    __shared__ float gbuf[4 * 528];   // gates: block p stride 528, elem j*4+s

    float c;
    if (c0 == 0) {
        hbuf[(j_ >> 5) * 132 + (j_ & 31) * 4 + s_] = 0.0f;
        c = 0.0f;
    } else {
        hbuf[(j_ >> 5) * 132 + (j_ & 31) * 4 + s_] =
            state[((size_t)(dir * B_ + b0 + s_) * 2 + 0) * H_ + j_];
        c = state[((size_t)(dir * B_ + b0 + s_) * 2 + 1) * H_ + j_];
    }

    const int t0    = dir ? (L_ - 1 - c0) : c0;
    const int hstep = dir ? -D_ : D_;
    const int grow  = g2 + 128 * q;   // the gate row this lane writes

    const float* xp[4];
#pragma unroll
    for (int s = 0; s < 4; ++s)
        xp[s] = xgc + ((size_t)(dir * B_ + b0 + s) * tc) * G4H_ + grow;
    float* hp = hcat + ((size_t)(b0 + s_) * L_ + t0) * D_ + dir * H_ + j_;

    const float* hq = hbuf + q * 132; // this lane's k-quarter of h

    __syncthreads();

    for (int t = 0; t < tc; ++t) {
        float xv[4];
#pragma unroll
        for (int s = 0; s < 4; ++s) { xv[s] = xp[s][0]; xp[s] += G4H_; }

        float acc[4][4];
#pragma unroll
        for (int p = 0; p < 4; ++p)
#pragma unroll
            for (int s = 0; s < 4; ++s) acc[p][s] = 0.0f;

#pragma unroll
        for (int kk = 0; kk < 32; ++kk) {
            const float4 hv = *(const float4*)(hq + kk * 4);
#pragma unroll
            for (int p = 0; p < 4; ++p) {
                acc[p][0] += w[p][kk] * hv.x;
                acc[p][1] += w[p][kk] * hv.y;
                acc[p][2] += w[p][kk] * hv.z;
                acc[p][3] += w[p][kk] * hv.w;
            }
        }

#pragma unroll
        for (int p = 0; p < 4; ++p)
#pragma unroll
            for (int s = 0; s < 4; ++s) {
                float v = acc[p][s];
                v = dpp_add_<0xB1>(v);
                v = dpp_add_<0x4E>(v);
                acc[p][s] = v;
            }

        float o0 = acc[0][0], o1 = acc[0][1], o2 = acc[0][2], o3 = acc[0][3];
        if (q == 1) { o0 = acc[1][0]; o1 = acc[1][1]; o2 = acc[1][2]; o3 = acc[1][3]; }
        if (q == 2) { o0 = acc[2][0]; o1 = acc[2][1]; o2 = acc[2][2]; o3 = acc[2][3]; }
        if (q == 3) { o0 = acc[3][0]; o1 = acc[3][1]; o2 = acc[3][2]; o3 = acc[3][3]; }
        *(float4*)(gbuf + q * 528 + g2 * 4) =
            make_float4(o0 + xv[0], o1 + xv[1], o2 + xv[2], o3 + xv[3]);
        __syncthreads();

        {
            const float gi = gbuf[0 * 528 + j_ * 4 + s_];
            const float gf = gbuf[1 * 528 + j_ * 4 + s_];
            const float gg = gbuf[2 * 528 + j_ * 4 + s_];
            const float go = gbuf[3 * 528 + j_ * 4 + s_];
            c = sigmoidf_(gf) * c + sigmoidf_(gi) * tanhf(gg);
            const float hv = sigmoidf_(go) * tanhf(c);
            hbuf[(j_ >> 5) * 132 + (j_ & 31) * 4 + s_] = hv;
            hp[0] = hv;
            hp += hstep;
        }
        __syncthreads();
    }

    state[((size_t)(dir * B_ + b0 + s_) * 2 + 0) * H_ + j_] =
        hbuf[(j_ >> 5) * 132 + (j_ & 31) * 4 + s_];
    state[((size_t)(dir * B_ + b0 + s_) * 2 + 1) * H_ + j_] = c;
}

// ---------------------------------------------------------------------------
// K3a: MLP1 as clean 128x256 GEMM: h1 = leaky(hcat @ W1^T + b1).
// ---------------------------------------------------------------------------
__global__ __launch_bounds__(256) void mlp1_gemm(
    const float* __restrict__ hcat,
    const float* __restrict__ W1, const float* __restrict__ b1,
    float* __restrict__ h1)
{
    __shared__ float As[2][XBK][XASTR];
    __shared__ float Bs[2][XBK][XBSTR];

    const int bm  = blockIdx.x;       // 0..799
    const int tid = threadIdx.x;
    const int tx = tid & 15;
    const int ty = tid >> 4;

    const int am = tid >> 1;
    const int ak = (tid & 1) * 4;

    const float* arow  = hcat + (size_t)(bm * XBM + am) * D_ + ak;
    const float* brow0 = W1 + (size_t)am * D_ + ak;
    const float* brow1 = W1 + (size_t)(128 + am) * D_ + ak;

    float acc[8][16];
#pragma unroll
    for (int i = 0; i < 8; ++i)
#pragma unroll
        for (int j = 0; j < 16; ++j) acc[i][j] = 0.0f;

    {
        const float4 a  = *(const float4*)(arow);
        const float4 b0 = *(const float4*)(brow0);
        const float4 b1v = *(const float4*)(brow1);
        As[0][ak + 0][am] = a.x;  As[0][ak + 1][am] = a.y;
        As[0][ak + 2][am] = a.z;  As[0][ak + 3][am] = a.w;
        Bs[0][ak + 0][am] = b0.x; Bs[0][ak + 1][am] = b0.y;
        Bs[0][ak + 2][am] = b0.z; Bs[0][ak + 3][am] = b0.w;
        Bs[0][ak + 0][128 + am] = b1v.x; Bs[0][ak + 1][128 + am] = b1v.y;
        Bs[0][ak + 2][128 + am] = b1v.z; Bs[0][ak + 3][128 + am] = b1v.w;
    }
    __syncthreads();

    const int NIT = D_ / XBK;         // 32
    for (int it = 0; it < NIT; ++it) {
        const int cur = it & 1;
        const int kn  = (it + 1) * XBK;
        float4 na, nb0, nb1;
        if (kn < D_) {
            na  = *(const float4*)(arow + kn);
            nb0 = *(const float4*)(brow0 + kn);
            nb1 = *(const float4*)(brow1 + kn);
        }
#pragma unroll
        for (int k = 0; k < XBK; ++k) {
            float a[8], bb[16];
            *(float4*)a         = *(const float4*)&As[cur][k][ty * 4];
            *(float4*)(a + 4)   = *(const float4*)&As[cur][k][64 + ty * 4];
            *(float4*)(bb)      = *(const float4*)&Bs[cur][k][tx * 4];
            *(float4*)(bb + 4)  = *(const float4*)&Bs[cur][k][64 + tx * 4];
            *(float4*)(bb + 8)  = *(const float4*)&Bs[cur][k][128 + tx * 4];
            *(float4*)(bb + 12) = *(const float4*)&Bs[cur][k][192 + tx * 4];
#pragma unroll
            for (int i = 0; i < 8; ++i)
#pragma unroll
                for (int j = 0; j < 16; ++j) acc[i][j] += a[i] * bb[j];
        }
        if (kn < D_) {
            const int nxt = cur ^ 1;
            As[nxt][ak + 0][am] = na.x;  As[nxt][ak + 1][am] = na.y;
            As[nxt][ak + 2][am] = na.z;  As[nxt][ak + 3][am] = na.w;
            Bs[nxt][ak + 0][am] = nb0.x; Bs[nxt][ak + 1][am] = nb0.y;
            Bs[nxt][ak + 2][am] = nb0.z; Bs[nxt][ak + 3][am] = nb0.w;
            Bs[nxt][ak + 0][128 + am] = nb1.x; Bs[nxt][ak + 1][128 + am] = nb1.y;
            Bs[nxt][ak + 2][128 + am] = nb1.z; Bs[nxt][ak + 3][128 + am] = nb1.w;
        }
        __syncthreads();
    }

    float bias[16];
#pragma unroll
    for (int qd = 0; qd < 4; ++qd) {
        const int cb = qd * 64 + tx * 4;
#pragma unroll
        for (int j = 0; j < 4; ++j) bias[qd * 4 + j] = b1[cb + j];
    }
#pragma unroll
    for (int i = 0; i < 8; ++i) {
        const int row = bm * XBM + ((i < 4) ? (ty * 4 + i) : (64 + ty * 4 + i - 4));
        float* dst = h1 + (size_t)row * D_;
#pragma unroll
        for (int qd = 0; qd < 4; ++qd) {
            float4 v;
            v.x = leakyf_(acc[i][qd * 4 + 0] + bias[qd * 4 + 0]);
            v.y = leakyf_(acc[i][qd * 4 + 1] + bias[qd * 4 + 1]);
            v.z = leakyf_(acc[i][qd * 4 + 2] + bias[qd * 4 + 2]);
            v.w = leakyf_(acc[i][qd * 4 + 3] + bias[qd * 4 + 3]);
            *(float4*)(dst + qd * 64 + tx * 4) = v;
        }
    }
}

// ---------------------------------------------------------------------------
// K3b: MLP2 + tag projection: h2 = leaky(h1 @ W2^T + b2) (in regs),
// logits = leaky(h2 @ Wt^T + bt) via per-thread partials + 16-lane shfl.
// ---------------------------------------------------------------------------
__global__ __launch_bounds__(256) void mlp2tag(
    const float* __restrict__ h1,
    const float* __restrict__ W2, const float* __restrict__ b2,
    const float* __restrict__ Wt, const float* __restrict__ bt,
    float* __restrict__ logits)
{
    __shared__ float As[2][XBK][XASTR];
    __shared__ float Bs[2][XBK][XBSTR];
    __shared__ float Wt_s[T_][D_ + 2];
    __shared__ float b2_s[D_];
    __shared__ float bt_s[T_];

    const int bm  = blockIdx.x;       // 0..799
    const int tid = threadIdx.x;
    const int tx = tid & 15;
    const int ty = tid >> 4;

    for (int i = tid; i < T_ * D_; i += 256) Wt_s[i >> 8][i & 255] = Wt[i];
    b2_s[tid] = b2[tid];
    if (tid < T_) bt_s[tid] = bt[tid];

    const int am = tid >> 1;
    const int ak = (tid & 1) * 4;

    const float* arow  = h1 + (size_t)(bm * XBM + am) * D_ + ak;
    const float* brow0 = W2 + (size_t)am * D_ + ak;
    const float* brow1 = W2 + (size_t)(128 + am) * D_ + ak;

    float acc[8][16];
#pragma unroll
    for (int i = 0; i < 8; ++i)
#pragma unroll
        for (int j = 0; j < 16; ++j) acc[i][j] = 0.0f;

    {
        const float4 a  = *(const float4*)(arow);
        const float4 b0 = *(const float4*)(brow0);
        const float4 b1v = *(const float4*)(brow1);
        As[0][ak + 0][am] = a.x;  As[0][ak + 1][am] = a.y;
        As[0][ak + 2][am] = a.z;  As[0][ak + 3][am] = a.w;
        Bs[0][ak + 0][am] = b0.x; Bs[0][ak + 1][am] = b0.y;
        Bs[0][ak + 2][am] = b0.z; Bs[0][ak + 3][am] = b0.w;
        Bs[0][ak + 0][128 + am] = b1v.x; Bs[0][ak + 1][128 + am] = b1v.y;
        Bs[0][ak + 2][128 + am] = b1v.z; Bs[0][ak + 3][128 + am] = b1v.w;
    }
    __syncthreads();

    const int NIT = D_ / XBK;         // 32
    for (int it = 0; it < NIT; ++it) {
        const int cur = it & 1;
        const int kn  = (it + 1) * XBK;
        float4 na, nb0, nb1;
        if (kn < D_) {
            na  = *(const float4*)(arow + kn);
            nb0 = *(const float4*)(brow0 + kn);
            nb1 = *(const float4*)(brow1 + kn);
        }
#pragma unroll
        for (int k = 0; k < XBK; ++k) {
            float a[8], bb[16];
            *(float4*)a         = *(const float4*)&As[cur][k][ty * 4];
            *(float4*)(a + 4)   = *(const float4*)&As[cur][k][64 + ty * 4];
            *(float4*)(bb)      = *(const float4*)&Bs[cur][k][tx * 4];
            *(float4*)(bb + 4)  = *(const float4*)&Bs[cur][k][64 + tx * 4];
            *(float4*)(bb + 8)  = *(const float4*)&Bs[cur][k][128 + tx * 4];
            *(float4*)(bb + 12) = *(const float4*)&Bs[cur][k][192 + tx * 4];
#pragma unroll
            for (int i = 0; i < 8; ++i)
#pragma unroll
                for (int j = 0; j < 16; ++j) acc[i][j] += a[i] * bb[j];
        }
        if (kn < D_) {
            const int nxt = cur ^ 1;
            As[nxt][ak + 0][am] = na.x;  As[nxt][ak + 1][am] = na.y;
            As[nxt][ak + 2][am] = na.z;  As[nxt][ak + 3][am] = na.w;
            Bs[nxt][ak + 0][am] = nb0.x; Bs[nxt][ak + 1][am] = nb0.y;
            Bs[nxt][ak + 2][am] = nb0.z; Bs[nxt][ak + 3][am] = nb0.w;
            Bs[nxt][ak + 0][128 + am] = nb1.x; Bs[nxt][ak + 1][128 + am] = nb1.y;
            Bs[nxt][ak + 2][128 + am] = nb1.z; Bs[nxt][ak + 3][128 + am] = nb1.w;
        }
        __syncthreads();
    }

    // epilogue: h2 = leaky(acc + b2); tag partials over this thread's 16 cols
    float part[8][T_];
#pragma unroll
    for (int i = 0; i < 8; ++i)
#pragma unroll
        for (int jt = 0; jt < T_; ++jt) part[i][jt] = 0.0f;

#pragma unroll
    for (int j = 0; j < 16; ++j) {
        const int n = (j >> 2) * 64 + tx * 4 + (j & 3);
        const float bv = b2_s[n];
        float h2v[8];
#pragma unroll
        for (int i = 0; i < 8; ++i) h2v[i] = leakyf_(acc[i][j] + bv);
#pragma unroll
        for (int jt = 0; jt < T_; ++jt) {
            const float wv = Wt_s[jt][n];
#pragma unroll
            for (int i = 0; i < 8; ++i) part[i][jt] += h2v[i] * wv;
        }
    }

#pragma unroll
    for (int m = 1; m <= 8; m <<= 1)
#pragma unroll
        for (int i = 0; i < 8; ++i)
#pragma unroll
            for (int jt = 0; jt < T_; ++jt)
                part[i][jt] += __shfl_xor(part[i][jt], m, 16);

    if (tx == 0) {
#pragma unroll
        for (int i = 0; i < 8; ++i) {
            const int row = bm * XBM + ((i < 4) ? (ty * 4 + i) : (64 + ty * 4 + i - 4));
#pragma unroll
            for (int jt = 0; jt < T_; ++jt)
                logits[(size_t)row * T_ + jt] = leakyf_(part[i][jt] + bt_s[jt]);
        }
    }
}

// ---------------------------------------------------------------------------
// K3 (FALLBACK): fused MLP — previous version, used only if ws can't hold h1.
// ---------------------------------------------------------------------------
#define BM 64
#define BN 128
#define BK 16
#define ASTR 68
#define BSTR 132
#define S1T 68

__global__ __launch_bounds__(256) void fused_mlp(
    const float* __restrict__ hcat,
    const float* __restrict__ W1, const float* __restrict__ b1,
    const float* __restrict__ W2, const float* __restrict__ b2,
    const float* __restrict__ Wt, const float* __restrict__ bt,
    float* __restrict__ logits)
{
    __shared__ float As[BK][ASTR];
    __shared__ float Bs[BK][BSTR];
    __shared__ float h1T[BN][S1T];
    __shared__ float Wt_s[T_][D_ + 2];
    __shared__ float b1_s[D_], b2_s[D_], bt_s[T_];

    const int tid  = threadIdx.x;
    const int row0 = blockIdx.x * BM;

    for (int i = tid; i < T_ * D_; i += 256) Wt_s[i >> 8][i & 255] = Wt[i];
    b1_s[tid] = b1[tid];
    b2_s[tid] = b2[tid];
    if (tid < T_) bt_s[tid] = bt[tid];

    const int tx = tid & 15;
    const int ty = tid >> 4;
    const int lrow = tid >> 2;
    const int lk   = (tid & 3) * 4;

    const float* arow = hcat + (size_t)(row0 + lrow) * D_ + lk;

    float acc2[2][4][8];
#pragma unroll
    for (int q = 0; q < 2; ++q)
#pragma unroll
        for (int i = 0; i < 4; ++i)
#pragma unroll
            for (int j = 0; j < 8; ++j) acc2[q][i][j] = 0.0f;

    for (int n0t = 0; n0t < 2; ++n0t) {
        const int n0 = n0t * BN;

        float acc1[4][8];
#pragma unroll
        for (int i = 0; i < 4; ++i)
#pragma unroll
            for (int j = 0; j < 8; ++j) acc1[i][j] = 0.0f;

        for (int k0 = 0; k0 < D_; k0 += BK) {
            {
                const float4 v = *(const float4*)(arow + k0);
                As[lk + 0][lrow] = v.x; As[lk + 1][lrow] = v.y;
                As[lk + 2][lrow] = v.z; As[lk + 3][lrow] = v.w;
            }
#pragma unroll
            for (int p = 0; p < 2; ++p) {
                const int n = p * 64 + lrow;
                const float4 v = *(const float4*)(W1 + (size_t)(n0 + n) * D_ + k0 + lk);
                Bs[lk + 0][n] = v.x; Bs[lk + 1][n] = v.y;
                Bs[lk + 2][n] = v.z; Bs[lk + 3][n] = v.w;
            }
            __syncthreads();
#pragma unroll
            for (int k = 0; k < BK; ++k) {
                float a[4], bb[8];
                *(float4*)a        = *(const float4*)&As[k][ty * 4];
                *(float4*)(bb)     = *(const float4*)&Bs[k][tx * 4];
                *(float4*)(bb + 4) = *(const float4*)&Bs[k][64 + tx * 4];
#pragma unroll
                for (int i = 0; i < 4; ++i)
#pragma unroll
                    for (int j = 0; j < 8; ++j) acc1[i][j] += a[i] * bb[j];
            }
            __syncthreads();
        }

#pragma unroll
        for (int j = 0; j < 8; ++j) {
            const int nl = (j < 4) ? (tx * 4 + j) : (64 + tx * 4 + j - 4);
            const float bv = b1_s[n0 + nl];
            float4 v;
            v.x = leakyf_(acc1[0][j] + bv);
            v.y = leakyf_(acc1[1][j] + bv);
            v.z = leakyf_(acc1[2][j] + bv);
            v.w = leakyf_(acc1[3][j] + bv);
            *(float4*)&h1T[nl][ty * 4] = v;
        }
        __syncthreads();

#pragma unroll
        for (int n2t = 0; n2t < 2; ++n2t) {
            for (int kc = 0; kc < BN; kc += BK) {
#pragma unroll
                for (int p = 0; p < 2; ++p) {
                    const int n = p * 64 + lrow;
                    const float4 v = *(const float4*)(W2 + (size_t)(n2t * BN + n) * D_ + n0 + kc + lk);
                    Bs[lk + 0][n] = v.x; Bs[lk + 1][n] = v.y;
                    Bs[lk + 2][n] = v.z; Bs[lk + 3][n] = v.w;
                }
                __syncthreads();
#pragma unroll
                for (int k = 0; k < BK; ++k) {
                    float a[4], bb[8];
                    *(float4*)a        = *(const float4*)&h1T[kc + k][ty * 4];
                    *(float4*)(bb)     = *(const float4*)&Bs[k][tx * 4];
                    *(float4*)(bb + 4) = *(const float4*)&Bs[k][64 + tx * 4];
#pragma unroll
                    for (int i = 0; i < 4; ++i)
#pragma unroll
                        for (int j = 0; j < 8; ++j) acc2[n2t][i][j] += a[i] * bb[j];
                }
                __syncthreads();
            }
        }
    }

    float part[4][T_];
#pragma unroll
    for (int i = 0; i < 4; ++i)
#pragma unroll
        for (int jt = 0; jt < T_; ++jt) part[i][jt] = 0.0f;

#pragma unroll
    for (int q = 0; q < 2; ++q)
#pragma unroll
        for (int j = 0; j < 8; ++j) {
            const int n = q * BN + ((j < 4) ? (tx * 4 + j) : (64 + tx * 4 + j - 4));
            const float bv = b2_s[n];
            float h2v[4];
#pragma unroll
            for (int i = 0; i < 4; ++i) h2v[i] = leakyf_(acc2[q][i][j] + bv);
#pragma unroll
            for (int jt = 0; jt < T_; ++jt) {
                const float wv = Wt_s[jt][n];
#pragma unroll
                for (int i = 0; i < 4; ++i) part[i][jt] += h2v[i] * wv;
            }
        }

#pragma unroll
    for (int m = 1; m <= 8; m <<= 1)
#pragma unroll
        for (int i = 0; i < 4; ++i)
#pragma unroll
            for (int jt = 0; jt < T_; ++jt)
                part[i][jt] += __shfl_xor(part[i][jt], m, 16);

    if (tx == 0) {
#pragma unroll
        for (int i = 0; i < 4; ++i) {
            const int m = row0 + ty * 4 + i;
#pragma unroll
            for (int jt = 0; jt < T_; ++jt)
                logits[(size_t)m * T_ + jt] = leakyf_(part[i][jt] + bt_s[jt]);
        }
    }
}

// ---------------------------------------------------------------------------
// K4: Viterbi per sample — unchanged.
// ---------------------------------------------------------------------------
__global__ __launch_bounds__(64) void viterbi_kernel(
    const float* __restrict__ logits, const float* __restrict__ trans,
    float* __restrict__ out)
{
    const int b = blockIdx.x;
    const int lane = threadIdx.x;

    __shared__ unsigned char bp[L_][8];
    __shared__ int path_s[L_];

    float tr[T_];
    if (lane < T_) {
#pragma unroll
        for (int i = 0; i < T_; ++i) tr[i] = trans[i * T_ + lane];
    }
    const float* lg = logits + (size_t)b * L_ * T_;
    float prev = (lane < T_) ? lg[lane] : -1e30f;

    for (int t = 1; t < L_; ++t) {
        float m = -1e30f; int arg = 0;
#pragma unroll
        for (int i = 0; i < T_; ++i) {
            const float v = __shfl(prev, i, 64) + tr[i];
            if (v > m) { m = v; arg = i; }
        }
        const float obs = (lane < T_) ? lg[t * T_ + lane] : 0.0f;
        prev = obs + m;
        if (lane < T_) bp[t][lane] = (unsigned char)arg;
    }
    __syncthreads();

    float best = __shfl(prev, 0, 64); int tag = 0;
#pragma unroll
    for (int jj = 1; jj < T_; ++jj) {
        const float v = __shfl(prev, jj, 64);
        if (v > best) { best = v; tag = jj; }
    }
    if (lane == 0) {
        out[b] = best;
        path_s[L_ - 1] = tag;
        for (int t = L_ - 1; t >= 1; --t) {
            tag = bp[t][tag];
            path_s[t - 1] = tag;
        }
    }
    __syncthreads();
    for (int i = lane; i < L_; i += 64)
        out[B_ + (size_t)b * L_ + i] = (float)path_s[i];
}

// ---------------------------------------------------------------------------
extern "C" void kernel_launch(void* const* d_in, const int* in_sizes, int n_in,
                              void* d_out, int out_size, void* d_ws, size_t ws_size,
                              hipStream_t stream)
{
    (void)in_sizes; (void)n_in; (void)out_size;

    const int*   sent  = (const int*)  d_in[0];
    const float* emb   = (const float*)d_in[2];
    const float* Wih_f = (const float*)d_in[3];
    const float* Whh_f = (const float*)d_in[4];
    const float* bih_f = (const float*)d_in[5];
    const float* bhh_f = (const float*)d_in[6];
    const float* Wih_b = (const float*)d_in[7];
    const float* Whh_b = (const float*)d_in[8];
    const float* bih_b = (const float*)d_in[9];
    const float* bhh_b = (const float*)d_in[10];
    const float* W1    = (const float*)d_in[11];
    const float* b1    = (const float*)d_in[12];
    const float* W2    = (const float*)d_in[13];
    const float* b2    = (const float*)d_in[14];
    const float* Wt    = (const float*)d_in[15];
    const float* bt    = (const float*)d_in[16];
    const float* trans = (const float*)d_in[17];

    float* ws = (float*)d_ws;
    const size_t HCAT_E = (size_t)B_ * L_ * D_;     // 26,214,400 floats
    const size_t LG_E   = (size_t)B_ * L_ * T_;     //    614,400
    const size_t ST_E   = (size_t)2 * B_ * 2 * H_;  //    262,144
    const size_t H1_E   = HCAT_E;                   // h1 is B*L*D too
    float* hcat   = ws;
    float* logits = ws + HCAT_E;
    float* state  = logits + LG_E;
    float* xgc    = state + ST_E;

    // Adaptive time-chunk so the xg staging buffer fits in ws_size.
    // (measured: ws in [249,312) MB -> 3 chunks; P-table path infeasible)
    const size_t base  = HCAT_E + LG_E + ST_E;      // ~108 MB
    const size_t per_t = (size_t)2 * B_ * G4H_;     // 524,288 floats per timestep
    const size_t ws_f  = ws_size / sizeof(float);
    long long avail = (long long)ws_f - (long long)base;
    int Tc = (avail > 0) ? (int)(avail / (long long)per_t) : 0;
    if (Tc < 1)  Tc = 1;
    if (Tc > L_) Tc = L_;

    float* out = (float*)d_out;

    for (int c0 = 0; c0 < L_; c0 += Tc) {
        const int tc = (L_ - c0 < Tc) ? (L_ - c0) : Tc;
        gemm_xg_chunk<<<dim3(8 * tc, 2), 256, 0, stream>>>(
            sent, emb, Wih_f, Wih_b, bih_f, bhh_f, bih_b, bhh_b, xgc, c0, tc);
        lstm_scan_chunk<<<256, 512, 0, stream>>>(
            xgc, Whh_f, Whh_b, state, hcat, c0, tc);
    }

    if (avail >= (long long)H1_E) {
        // h1 aliases xgc: the LSTM phase is done with xgc before mlp1 runs.
        float* h1 = xgc;
        mlp1_gemm<<<(B_ * L_) / XBM, 256, 0, stream>>>(hcat, W1, b1, h1);
        mlp2tag<<<(B_ * L_) / XBM, 256, 0, stream>>>(h1, W2, b2, Wt, bt, logits);
    } else {
        fused_mlp<<<(B_ * L_) / BM, 256, 0, stream>>>(
            hcat, W1, b1, W2, b2, Wt, bt, logits);
    }
    viterbi_kernel<<<B_, 64, 0, stream>>>(logits, trans, out);
}

// Round 6
// 1786.008 us; speedup vs baseline: 1.2783x; 1.2783x over previous
//
#include <hip/hip_runtime.h>
#include <cmath>

// Problem constants
#define B_   512
#define L_   200
#define V_   50000
#define E_   256
#define H_   128     // per-direction hidden
#define G4H_ 512     // 4*H
#define D_   256     // 2*H
#define T_   6

__device__ __forceinline__ float sigmoidf_(float x) { return 1.0f / (1.0f + __expf(-x)); }
__device__ __forceinline__ float leakyf_(float x)   { return x >= 0.0f ? x : 0.01f * x; }

// DPP quad-perm add (VALU pipe — NOT ds_bpermute/LDS). CTRL: xor1=0xB1, xor2=0x4E.
template<int CTRL>
__device__ __forceinline__ float dpp_add_(float x) {
    const int m = __builtin_amdgcn_mov_dpp(__float_as_int(x), CTRL, 0xF, 0xF, true);
    return x + __int_as_float(m);
}

// ---------------------------------------------------------------------------
// K1: xg GEMM, 128x128 tile, 8x8 micro-tile, BK=8, ping-pong double buffer.
// (REVERTED to round-3 measured-good config: VGPR ~160 -> 3-4 waves/SIMD.
//  Round-5 lesson: 256-wide tile kept the same LDS:FMA instruction ratio but
//  halved occupancy (VGPR 196 -> 2 waves/SIMD) and regressed 280->416 us.)
// ---------------------------------------------------------------------------
#define XBM 128
#define XBN 128
#define XBK 8
#define XSTR 132

__global__ __launch_bounds__(256) void gemm_xg_chunk(
    const int* __restrict__ sent, const float* __restrict__ emb,
    const float* __restrict__ Wf, const float* __restrict__ Wb,
    const float* __restrict__ bihf, const float* __restrict__ bhhf,
    const float* __restrict__ bihb, const float* __restrict__ bhhb,
    float* __restrict__ xgc, int c0, int tc)
{
    __shared__ float As[2][XBK][XSTR];
    __shared__ float Bs[2][XBK][XSTR];
    __shared__ int   tok[XBM];

    const int bm  = blockIdx.x;       // 0 .. 8*tc-1
    const int bn  = blockIdx.y;       // 0..3 (N=512 per dir)
    const int tid = threadIdx.x;
    const int half = B_ * tc;         // rows per direction
    const int dir  = (bm * XBM) >= half;  // uniform (B*tc % 128 == 0)

    if (tid < XBM) {
        const int vm  = bm * XBM + tid;
        const int rem = vm - dir * half;
        const int b   = rem / tc;
        const int ti  = rem - b * tc;
        const int s   = c0 + ti;
        const int t   = dir ? (L_ - 1 - s) : s;
        tok[tid] = sent[b * L_ + t];
    }
    __syncthreads();

    const int tx = tid & 15;          // n quad: tx*4 and 64+tx*4
    const int ty = tid >> 4;          // m quad: ty*4 and 64+ty*4
    const int n0 = bn * XBN;

    const float* W   = dir ? Wb   : Wf;
    const float* bih = dir ? bihb : bihf;
    const float* bhh = dir ? bhhb : bhhf;

    const int am = tid >> 1;          // staging row 0..127
    const int ak = (tid & 1) * 4;     // staging k 0 or 4

    const float* arow = emb + (size_t)tok[am] * E_ + ak;
    const float* brow = W + (size_t)(n0 + am) * E_ + ak;

    float acc[8][8];
#pragma unroll
    for (int i = 0; i < 8; ++i)
#pragma unroll
        for (int j = 0; j < 8; ++j) acc[i][j] = 0.0f;

    // prologue: stage slice 0
    {
        const float4 a = *(const float4*)(arow);
        const float4 b = *(const float4*)(brow);
        As[0][ak + 0][am] = a.x; As[0][ak + 1][am] = a.y;
        As[0][ak + 2][am] = a.z; As[0][ak + 3][am] = a.w;
        Bs[0][ak + 0][am] = b.x; Bs[0][ak + 1][am] = b.y;
        Bs[0][ak + 2][am] = b.z; Bs[0][ak + 3][am] = b.w;
    }
    __syncthreads();

    const int NIT = E_ / XBK;         // 32
    for (int it = 0; it < NIT; ++it) {
        const int cur = it & 1;
        const int kn  = (it + 1) * XBK;
        float4 na, nb;
        if (kn < E_) {
            na = *(const float4*)(arow + kn);
            nb = *(const float4*)(brow + kn);
        }
#pragma unroll
        for (int k = 0; k < XBK; ++k) {
            float a[8], bb[8];
            *(float4*)a        = *(const float4*)&As[cur][k][ty * 4];
            *(float4*)(a + 4)  = *(const float4*)&As[cur][k][64 + ty * 4];
            *(float4*)(bb)     = *(const float4*)&Bs[cur][k][tx * 4];
            *(float4*)(bb + 4) = *(const float4*)&Bs[cur][k][64 + tx * 4];
#pragma unroll
            for (int i = 0; i < 8; ++i)
#pragma unroll
                for (int j = 0; j < 8; ++j) acc[i][j] += a[i] * bb[j];
        }
        if (kn < E_) {
            const int nxt = cur ^ 1;
            As[nxt][ak + 0][am] = na.x; As[nxt][ak + 1][am] = na.y;
            As[nxt][ak + 2][am] = na.z; As[nxt][ak + 3][am] = na.w;
            Bs[nxt][ak + 0][am] = nb.x; Bs[nxt][ak + 1][am] = nb.y;
            Bs[nxt][ak + 2][am] = nb.z; Bs[nxt][ak + 3][am] = nb.w;
        }
        __syncthreads();
    }

    // epilogue: bias + store.
    const int nb0i = n0 + tx * 4;
    const int nb1i = n0 + 64 + tx * 4;
    float bias[8];
#pragma unroll
    for (int j = 0; j < 4; ++j) {
        bias[j]     = bih[nb0i + j] + bhh[nb0i + j];
        bias[4 + j] = bih[nb1i + j] + bhh[nb1i + j];
    }
#pragma unroll
    for (int i = 0; i < 8; ++i) {
        const int row = bm * XBM + ((i < 4) ? (ty * 4 + i) : (64 + ty * 4 + i - 4));
        float* dst = xgc + (size_t)row * G4H_;
        float4 v0, v1;
        v0.x = acc[i][0] + bias[0]; v0.y = acc[i][1] + bias[1];
        v0.z = acc[i][2] + bias[2]; v0.w = acc[i][3] + bias[3];
        v1.x = acc[i][4] + bias[4]; v1.y = acc[i][5] + bias[5];
        v1.z = acc[i][6] + bias[6]; v1.w = acc[i][7] + bias[7];
        *(float4*)(dst + nb0i) = v0;
        *(float4*)(dst + nb1i) = v1;
    }
}

// ---------------------------------------------------------------------------
// K2 (v4): LSTM scan, 4-way split-K + DPP quad reduce, ONE barrier per step.
// After the DPP butterfly every lane of a quad holds all 4 gate row-sums for
// hidden j=g2, all 4 samples -> the v3 gbuf exchange was redundant. Lane
// (g2,q) finishes sample q in-register: loads its own 4 x-gates, selects
// acc[.][q] via static cndmask chain, applies the nonlinearity, writes new h
// into DOUBLE-BUFFERED hbuf[par^1] (no read/write race -> first barrier
// deleted). Per step removed: gbuf b128 write, 4 gbuf reads, 1 barrier.
// LDS: broadcast reads across quads hit disjoint banks; h-writes are
// tid-consecutive. VGPR ~180 < 256 cap (launch_bounds 512,2) -> no remat.
// ---------------------------------------------------------------------------
__global__ __launch_bounds__(512, 2) void lstm_scan_chunk(
    const float* __restrict__ xgc,
    const float* __restrict__ Whh_f, const float* __restrict__ Whh_b,
    float* __restrict__ state, float* __restrict__ hcat, int c0, int tc)
{
    const int wg  = blockIdx.x;      // 0..255
    const int dir = wg >> 7;
    const int b0  = (wg & 127) * 4;  // 4 samples per wg
    const int tid = threadIdx.x;     // 0..511

    const int q  = tid & 3;          // k-quarter AND this lane's sample
    const int g2 = tid >> 2;         // hidden j / gate-group 0..127

    const float* Whh = dir ? Whh_b : Whh_f;

    // quarter-rows of 4 gates: 4 x 32 = 128 VGPRs, statically indexed
    float w[4][32];
#pragma unroll
    for (int p = 0; p < 4; ++p) {
        const float* wr = Whh + (size_t)(g2 + 128 * p) * H_ + q * 32;
#pragma unroll
        for (int kk = 0; kk < 32; kk += 4) {
            const float4 v = *(const float4*)(wr + kk);
            w[p][kk] = v.x; w[p][kk + 1] = v.y; w[p][kk + 2] = v.z; w[p][kk + 3] = v.w;
        }
    }

    __shared__ float hbuf[2][4 * 132];   // [parity][quarter q'*132 + kk*4 + s]

    float c, hval;
    if (c0 == 0) {
        hval = 0.0f;
        c    = 0.0f;
    } else {
        hval = state[((size_t)(dir * B_ + b0 + q) * 2 + 0) * H_ + g2];
        c    = state[((size_t)(dir * B_ + b0 + q) * 2 + 1) * H_ + g2];
    }
    hbuf[0][(g2 >> 5) * 132 + (g2 & 31) * 4 + q] = hval;

    const int t0    = dir ? (L_ - 1 - c0) : c0;
    const int hstep = dir ? -D_ : D_;

    // this lane's sample-q x pointer; gates at +128p
    const float* xq = xgc + ((size_t)(dir * B_ + b0 + q) * tc) * G4H_ + g2;
    float* hp = hcat + ((size_t)(b0 + q) * L_ + t0) * D_ + dir * H_ + g2;

    __syncthreads();

    for (int t = 0; t < tc; ++t) {
        const int par = t & 1;
        const float* hq = &hbuf[par][q * 132];   // this lane's k-quarter of h

        // x for this lane's sample, all 4 gates (latency hides under the dot)
        float xg[4];
#pragma unroll
        for (int p = 0; p < 4; ++p) xg[p] = xq[128 * p];
        xq += G4H_;

        float acc[4][4];
#pragma unroll
        for (int p = 0; p < 4; ++p)
#pragma unroll
            for (int s = 0; s < 4; ++s) acc[p][s] = 0.0f;

#pragma unroll
        for (int kk = 0; kk < 32; ++kk) {
            const float4 hv = *(const float4*)(hq + kk * 4);
#pragma unroll
            for (int p = 0; p < 4; ++p) {
                acc[p][0] += w[p][kk] * hv.x;
                acc[p][1] += w[p][kk] * hv.y;
                acc[p][2] += w[p][kk] * hv.z;
                acc[p][3] += w[p][kk] * hv.w;
            }
        }

        // quad butterfly: afterwards every lane holds full row sums acc[p][s]
#pragma unroll
        for (int p = 0; p < 4; ++p)
#pragma unroll
            for (int s = 0; s < 4; ++s) {
                float v = acc[p][s];
                v = dpp_add_<0xB1>(v);
                v = dpp_add_<0x4E>(v);
                acc[p][s] = v;
            }

        // select this lane's sample (static indices only — rule #20)
        float gi = acc[0][0], gf = acc[1][0], gg = acc[2][0], go = acc[3][0];
        if (q == 1) { gi = acc[0][1]; gf = acc[1][1]; gg = acc[2][1]; go = acc[3][1]; }
        if (q == 2) { gi = acc[0][2]; gf = acc[1][2]; gg = acc[2][2]; go = acc[3][2]; }
        if (q == 3) { gi = acc[0][3]; gf = acc[1][3]; gg = acc[2][3]; go = acc[3][3]; }
        gi += xg[0]; gf += xg[1]; gg += xg[2]; go += xg[3];

        c    = sigmoidf_(gf) * c + sigmoidf_(gi) * tanhf(gg);
        hval = sigmoidf_(go) * tanhf(c);

        hbuf[par ^ 1][(g2 >> 5) * 132 + (g2 & 31) * 4 + q] = hval;
        hp[0] = hval;
        hp += hstep;
        __syncthreads();   // the ONLY barrier per step
    }

    state[((size_t)(dir * B_ + b0 + q) * 2 + 0) * H_ + g2] = hval;
    state[((size_t)(dir * B_ + b0 + q) * 2 + 1) * H_ + g2] = c;
}

// ---------------------------------------------------------------------------
// K3: fused MLP1 + MLP2 + tag projection — round-3 measured version (492 us).
// ---------------------------------------------------------------------------
#define BM 64
#define BN 128
#define BK 16
#define ASTR 68
#define BSTR 132
#define S1T 68   // h1T row stride

__global__ __launch_bounds__(256) void fused_mlp(
    const float* __restrict__ hcat,
    const float* __restrict__ W1, const float* __restrict__ b1,
    const float* __restrict__ W2, const float* __restrict__ b2,
    const float* __restrict__ Wt, const float* __restrict__ bt,
    float* __restrict__ logits)
{
    __shared__ float As[BK][ASTR];      // hcat k-slice, [k][m]
    __shared__ float Bs[BK][BSTR];      // W slice, [k][n]
    __shared__ float h1T[BN][S1T];      // h1 chunk, [k_local][m]
    __shared__ float Wt_s[T_][D_ + 2];
    __shared__ float b1_s[D_], b2_s[D_], bt_s[T_];

    const int tid  = threadIdx.x;
    const int row0 = blockIdx.x * BM;

    for (int i = tid; i < T_ * D_; i += 256) Wt_s[i >> 8][i & 255] = Wt[i];
    b1_s[tid] = b1[tid];
    b2_s[tid] = b2[tid];
    if (tid < T_) bt_s[tid] = bt[tid];

    const int tx = tid & 15;
    const int ty = tid >> 4;
    const int lrow = tid >> 2;          // staging row 0..63
    const int lk   = (tid & 3) * 4;     // staging k 0,4,8,12

    const float* arow = hcat + (size_t)(row0 + lrow) * D_ + lk;

    float acc2[2][4][8];
#pragma unroll
    for (int q = 0; q < 2; ++q)
#pragma unroll
        for (int i = 0; i < 4; ++i)
#pragma unroll
            for (int j = 0; j < 8; ++j) acc2[q][i][j] = 0.0f;

    for (int n0t = 0; n0t < 2; ++n0t) {
        const int n0 = n0t * BN;

        // ---- GEMM1: h1[:, n0:n0+128] = hcat_tile @ W1^T ----
        float acc1[4][8];
#pragma unroll
        for (int i = 0; i < 4; ++i)
#pragma unroll
            for (int j = 0; j < 8; ++j) acc1[i][j] = 0.0f;

        for (int k0 = 0; k0 < D_; k0 += BK) {
            {
                const float4 v = *(const float4*)(arow + k0);
                As[lk + 0][lrow] = v.x; As[lk + 1][lrow] = v.y;
                As[lk + 2][lrow] = v.z; As[lk + 3][lrow] = v.w;
            }
#pragma unroll
            for (int p = 0; p < 2; ++p) {
                const int n = p * 64 + lrow;
                const float4 v = *(const float4*)(W1 + (size_t)(n0 + n) * D_ + k0 + lk);
                Bs[lk + 0][n] = v.x; Bs[lk + 1][n] = v.y;
                Bs[lk + 2][n] = v.z; Bs[lk + 3][n] = v.w;
            }
            __syncthreads();
#pragma unroll
            for (int k = 0; k < BK; ++k) {
                float a[4], bb[8];
                *(float4*)a        = *(const float4*)&As[k][ty * 4];
                *(float4*)(bb)     = *(const float4*)&Bs[k][tx * 4];
                *(float4*)(bb + 4) = *(const float4*)&Bs[k][64 + tx * 4];
#pragma unroll
                for (int i = 0; i < 4; ++i)
#pragma unroll
                    for (int j = 0; j < 8; ++j) acc1[i][j] += a[i] * bb[j];
            }
            __syncthreads();
        }

        // h1 (+bias, leaky) -> h1T[k_local][m]
#pragma unroll
        for (int j = 0; j < 8; ++j) {
            const int nl = (j < 4) ? (tx * 4 + j) : (64 + tx * 4 + j - 4);
            const float bv = b1_s[n0 + nl];
            float4 v;
            v.x = leakyf_(acc1[0][j] + bv);
            v.y = leakyf_(acc1[1][j] + bv);
            v.z = leakyf_(acc1[2][j] + bv);
            v.w = leakyf_(acc1[3][j] + bv);
            *(float4*)&h1T[nl][ty * 4] = v;
        }
        __syncthreads();

        // ---- GEMM2 partial: acc2 += h1[:, n0:+128] @ W2[:, n0:+128]^T ----
#pragma unroll
        for (int n2t = 0; n2t < 2; ++n2t) {
            for (int kc = 0; kc < BN; kc += BK) {
#pragma unroll
                for (int p = 0; p < 2; ++p) {
                    const int n = p * 64 + lrow;
                    const float4 v = *(const float4*)(W2 + (size_t)(n2t * BN + n) * D_ + n0 + kc + lk);
                    Bs[lk + 0][n] = v.x; Bs[lk + 1][n] = v.y;
                    Bs[lk + 2][n] = v.z; Bs[lk + 3][n] = v.w;
                }
                __syncthreads();
#pragma unroll
                for (int k = 0; k < BK; ++k) {
                    float a[4], bb[8];
                    *(float4*)a        = *(const float4*)&h1T[kc + k][ty * 4];
                    *(float4*)(bb)     = *(const float4*)&Bs[k][tx * 4];
                    *(float4*)(bb + 4) = *(const float4*)&Bs[k][64 + tx * 4];
#pragma unroll
                    for (int i = 0; i < 4; ++i)
#pragma unroll
                        for (int j = 0; j < 8; ++j) acc2[n2t][i][j] += a[i] * bb[j];
                }
                __syncthreads();
            }
        }
    }

    // ---- epilogue: h2 = leaky(acc2 + b2); tag partials; shfl reduce ----
    float part[4][T_];
#pragma unroll
    for (int i = 0; i < 4; ++i)
#pragma unroll
        for (int jt = 0; jt < T_; ++jt) part[i][jt] = 0.0f;

#pragma unroll
    for (int q = 0; q < 2; ++q)
#pragma unroll
        for (int j = 0; j < 8; ++j) {
            const int n = q * BN + ((j < 4) ? (tx * 4 + j) : (64 + tx * 4 + j - 4));
            const float bv = b2_s[n];
            float h2v[4];
#pragma unroll
            for (int i = 0; i < 4; ++i) h2v[i] = leakyf_(acc2[q][i][j] + bv);
#pragma unroll
            for (int jt = 0; jt < T_; ++jt) {
                const float wv = Wt_s[jt][n];
#pragma unroll
                for (int i = 0; i < 4; ++i) part[i][jt] += h2v[i] * wv;
            }
        }

#pragma unroll
    for (int m = 1; m <= 8; m <<= 1)
#pragma unroll
        for (int i = 0; i < 4; ++i)
#pragma unroll
            for (int jt = 0; jt < T_; ++jt)
                part[i][jt] += __shfl_xor(part[i][jt], m, 16);

    if (tx == 0) {
#pragma unroll
        for (int i = 0; i < 4; ++i) {
            const int m = row0 + ty * 4 + i;
#pragma unroll
            for (int jt = 0; jt < T_; ++jt)
                logits[(size_t)m * T_ + jt] = leakyf_(part[i][jt] + bt_s[jt]);
        }
    }
}

// ---------------------------------------------------------------------------
// K4: Viterbi per sample — unchanged.
// ---------------------------------------------------------------------------
__global__ __launch_bounds__(64) void viterbi_kernel(
    const float* __restrict__ logits, const float* __restrict__ trans,
    float* __restrict__ out)
{
    const int b = blockIdx.x;
    const int lane = threadIdx.x;

    __shared__ unsigned char bp[L_][8];
    __shared__ int path_s[L_];

    float tr[T_];   // tr[i] = trans[i][lane] for lane < T_
    if (lane < T_) {
#pragma unroll
        for (int i = 0; i < T_; ++i) tr[i] = trans[i * T_ + lane];
    }
    const float* lg = logits + (size_t)b * L_ * T_;
    float prev = (lane < T_) ? lg[lane] : -1e30f;

    for (int t = 1; t < L_; ++t) {
        float m = -1e30f; int arg = 0;
#pragma unroll
        for (int i = 0; i < T_; ++i) {
            const float v = __shfl(prev, i, 64) + tr[i];
            if (v > m) { m = v; arg = i; }
        }
        const float obs = (lane < T_) ? lg[t * T_ + lane] : 0.0f;
        prev = obs + m;
        if (lane < T_) bp[t][lane] = (unsigned char)arg;
    }
    __syncthreads();

    float best = __shfl(prev, 0, 64); int tag = 0;
#pragma unroll
    for (int jj = 1; jj < T_; ++jj) {
        const float v = __shfl(prev, jj, 64);
        if (v > best) { best = v; tag = jj; }
    }
    if (lane == 0) {
        out[b] = best;
        path_s[L_ - 1] = tag;
        for (int t = L_ - 1; t >= 1; --t) {
            tag = bp[t][tag];
            path_s[t - 1] = tag;
        }
    }
    __syncthreads();
    for (int i = lane; i < L_; i += 64)
        out[B_ + (size_t)b * L_ + i] = (float)path_s[i];
}

// ---------------------------------------------------------------------------
extern "C" void kernel_launch(void* const* d_in, const int* in_sizes, int n_in,
                              void* d_out, int out_size, void* d_ws, size_t ws_size,
                              hipStream_t stream)
{
    (void)in_sizes; (void)n_in; (void)out_size;

    const int*   sent  = (const int*)  d_in[0];
    const float* emb   = (const float*)d_in[2];
    const float* Wih_f = (const float*)d_in[3];
    const float* Whh_f = (const float*)d_in[4];
    const float* bih_f = (const float*)d_in[5];
    const float* bhh_f = (const float*)d_in[6];
    const float* Wih_b = (const float*)d_in[7];
    const float* Whh_b = (const float*)d_in[8];
    const float* bih_b = (const float*)d_in[9];
    const float* bhh_b = (const float*)d_in[10];
    const float* W1    = (const float*)d_in[11];
    const float* b1    = (const float*)d_in[12];
    const float* W2    = (const float*)d_in[13];
    const float* b2    = (const float*)d_in[14];
    const float* Wt    = (const float*)d_in[15];
    const float* bt    = (const float*)d_in[16];
    const float* trans = (const float*)d_in[17];

    float* ws = (float*)d_ws;
    const size_t HCAT_E = (size_t)B_ * L_ * D_;     // 26,214,400 floats
    const size_t LG_E   = (size_t)B_ * L_ * T_;     //    614,400
    const size_t ST_E   = (size_t)2 * B_ * 2 * H_;  //    262,144
    float* hcat   = ws;
    float* logits = ws + HCAT_E;
    float* state  = logits + LG_E;
    float* xgc    = state + ST_E;

    // Adaptive time-chunk so the xg staging buffer fits in ws_size.
    // (measured: ws in [249,312) MB -> 3 chunks; P-table path infeasible)
    const size_t base  = HCAT_E + LG_E + ST_E;      // ~108 MB
    const size_t per_t = (size_t)2 * B_ * G4H_;     // 524,288 floats per timestep
    const size_t ws_f  = ws_size / sizeof(float);
    long long avail = (long long)ws_f - (long long)base;
    int Tc = (avail > 0) ? (int)(avail / (long long)per_t) : 0;
    if (Tc < 1)  Tc = 1;
    if (Tc > L_) Tc = L_;

    float* out = (float*)d_out;

    for (int c0 = 0; c0 < L_; c0 += Tc) {
        const int tc = (L_ - c0 < Tc) ? (L_ - c0) : Tc;
        gemm_xg_chunk<<<dim3(8 * tc, 4), 256, 0, stream>>>(
            sent, emb, Wih_f, Wih_b, bih_f, bhh_f, bih_b, bhh_b, xgc, c0, tc);
        lstm_scan_chunk<<<256, 512, 0, stream>>>(
            xgc, Whh_f, Whh_b, state, hcat, c0, tc);
    }
    fused_mlp<<<(B_ * L_) / BM, 256, 0, stream>>>(
        hcat, W1, b1, W2, b2, Wt, bt, logits);
    viterbi_kernel<<<B_, 64, 0, stream>>>(logits, trans, out);
}